// Round 9
// baseline (276.482 us; speedup 1.0000x reference)
//
#include <hip/hip_runtime.h>
#include <math.h>

// ---------------------------------------------------------------------------
// EmergencyGNNEnhanced: encoder (32->256->128) -> 3x GCN (->64) -> edge MLP.
// CSR built on-device each call. agg[v] = dinv[v]*(sum_{u->v} y[u] + y[v]).
//
// R25: front-end re-pipelined with the PROVEN 256-thread encoder (R22's
// failure was the 512-thread encoder variant, not the overlap idea):
//   D1 prep0 (weights + btail zero)  D2 fill_part alone (~13us)
//   D3 mega_place_enc: fill_place(256-thr, pair-per-thread scans, 45KB LDS)
//      || encoder (unchanged 256-thr, 50KB LDS) -- union 50176B, 3 blk/CU.
// Replaces mega_fill_enc(45us, additive 13+32) + fill_place(18us exposed).
// Agg chain unchanged from R24 (f16 h state; bytes-bound at LLC rate).
// ---------------------------------------------------------------------------

#define N_NODES 100000
#define N_EDGES 1600000
#define N_EL    200000

#define KBUCK   196          // ceil(100000/512) windows of 512 nodes
#define WSHIFT  9
#define WMASK   511
#define BCAP    64           // LDS entries/bucket in pass A (chunk avg ~16)
#define BSTRIDE 12288        // scratch ints per bucket (seglen ~8.2k avg)
#define PART_NB 512
#define CHUNK   3125         // ceil(N_EDGES / PART_NB)
#define LCAP    10240        // pass-B LDS staging (seglen max ~8.8k)
#define ENC_NB  1563         // ceil(100000/64)

typedef __attribute__((ext_vector_type(8))) short short8_t;
typedef __attribute__((ext_vector_type(4))) float f32x4;

__device__ __forceinline__ unsigned short f2bf(float f) {
    unsigned u = __float_as_uint(f);
    unsigned r = u + 0x7FFFu + ((u >> 16) & 1u);   // RNE
    return (unsigned short)(r >> 16);
}

__device__ __forceinline__ float2 up16(unsigned u) {
    union { unsigned v; _Float16 h[2]; } c; c.v = u;
    return make_float2((float)c.h[0], (float)c.h[1]);
}

// ---------------- weight swizzle: fp32 W[K][N] -> bf16 B-fragment order -----
template<int KTOT, int NTOT>
__device__ __forceinline__ void wprep_one(const float* __restrict__ W, unsigned short* __restrict__ Wp, int flat) {
    if (flat >= KTOT * NTOT) return;
    int j = flat & 7, lane = (flat >> 3) & 63, kstep = (flat >> 9) & 1;
    int rest = flat >> 10;
    int ntile = rest % (NTOT / 16), chunk = rest / (NTOT / 16);
    int k = chunk * 64 + kstep * 32 + (lane >> 4) * 8 + j;
    int n = ntile * 16 + (lane & 15);
    Wp[flat] = f2bf(W[(size_t)k * NTOT + n]);
}

// K=32 variant (single k-step) for enc_w1 [32 x 256]
__device__ __forceinline__ void wprep32_one(const float* __restrict__ W, unsigned short* __restrict__ Wp, int flat) {
    if (flat >= 32 * 256) return;
    int j = flat & 7, lane = (flat >> 3) & 63, ntile = flat >> 9;   // 0..15
    int k = (lane >> 4) * 8 + j;
    int n = ntile * 16 + (lane & 15);
    Wp[flat] = f2bf(W[(size_t)k * 256 + n]);
}

// ---- prep0: ALL weight swizzles (blocks 0..319) + btail zero (block 320) ---
__global__ __launch_bounds__(256) void prep0(
    const float* w2, const float* w0, const float* w1, const float* wpp2, const float* w1e,
    const float* wc1, const float* wc2,
    unsigned short* p2, unsigned short* p0, unsigned short* p1, unsigned short* pp2,
    unsigned short* p1e, unsigned short* pc1, unsigned short* pc2,
    int* btail)
{
    int blk = blockIdx.x, t = threadIdx.x;
    if      (blk < 128) wprep_one<256, 128>(w2,  p2,  blk * 256 + t);
    else if (blk < 160) wprep_one<128,  64>(w0,  p0,  (blk - 128) * 256 + t);
    else if (blk < 224) wprep_one<128, 128>(w1,  p1,  (blk - 160) * 256 + t);
    else if (blk < 256) wprep_one<128,  64>(wpp2, pp2, (blk - 224) * 256 + t);
    else if (blk < 288) wprep32_one(w1e, p1e, (blk - 256) * 256 + t);
    else if (blk < 304) wprep_one< 64,  64>(wc1, pc1, (blk - 288) * 256 + t);
    else if (blk < 320) wprep_one< 64,  64>(wc2, pc2, (blk - 304) * 256 + t);
    else                btail[t] = 0;           // block 320: zero btail[0..255]
}

// ---------------- fill pass A (dst-window partition), standalone ------------
__global__ __launch_bounds__(256) void fill_part(const int* __restrict__ ei,
                                                 int* __restrict__ btail, int* __restrict__ bscr)
{
    __shared__ __align__(16) unsigned char sm[53568];
    int* base = (int*)sm;
    int (*lbuf)[BCAP] = (int(*)[BCAP])base;     // 12544 ints = 50176 B
    int* lcnt  = base + 12544;                  // 196
    int* offs  = base + 12740;                  // 197
    int* gbase = base + 12937;                  // 196
    int* sscan = base + 13133;                  // 256 -> end 53556 B
    int t = threadIdx.x;

    for (int i = t; i < KBUCK; i += 256) lcnt[i] = 0;
    __syncthreads();

    int e0   = blockIdx.x * CHUNK;
    int eend = e0 + CHUNK; if (eend > N_EDGES) eend = N_EDGES;
    for (int e = e0 + t; e < eend; e += 256) {
        int s = __builtin_nontemporal_load(ei + e);
        int d = __builtin_nontemporal_load(ei + N_EDGES + e);
        int b = d >> WSHIFT;
        int entry = ((d & WMASK) << 17) | s;
        int pos = atomicAdd(&lcnt[b], 1);
        if (pos < BCAP) lbuf[b][pos] = entry;
        else {                                  // statistical-skew spill (rare)
            int p = atomicAdd(&btail[b], 1);
            bscr[b * BSTRIDE + p] = entry;
        }
    }
    __syncthreads();

    int myc = 0;
    if (t < KBUCK) {
        myc = lcnt[t]; if (myc > BCAP) myc = BCAP;
        lcnt[t] = myc;
        gbase[t] = atomicAdd(&btail[t], myc);
    }
    // parallel inclusive scan of clamped counts -> offs[1..KBUCK]
    sscan[t] = (t < KBUCK) ? myc : 0;
    __syncthreads();
    for (int s = 1; s < 256; s <<= 1) {
        int a = (t >= s) ? sscan[t - s] : 0;
        __syncthreads();
        sscan[t] += a;
        __syncthreads();
    }
    if (t < KBUCK) offs[t + 1] = sscan[t];
    if (t == 0) offs[0] = 0;
    __syncthreads();

    int T = offs[KBUCK];
    for (int i = t; i < T; i += 256) {
        int loB = 0, hiB = KBUCK;               // binary search bucket
        while (hiB - loB > 1) { int mid = (loB + hiB) >> 1; if (offs[mid] <= i) loB = mid; else hiB = mid; }
        int j = i - offs[loB];
        bscr[loB * BSTRIDE + gbase[loB] + j] = lbuf[loB][j];
    }
}

// ---- fill_place body, 256 threads: thread t owns dst pair (2t, 2t+1) -------
// LDS: ssm 256 + lcnt 512 + lpre 256 + lbuf 10240 = 11264 ints = 45056 B.
__device__ __forceinline__ void fill_place_body256(unsigned char* sm, int b,
    const int* __restrict__ btail, const int* __restrict__ bscr,
    int* __restrict__ row_ptr, float* __restrict__ dinv, int* __restrict__ col)
{
    int* base = (int*)sm;
    int* ssm  = base;                           // 256
    int* lcnt = base + 256;                     // 512 (hist -> cursors)
    int* lpre = base + 768;                     // 256 (pair-sum scan)
    int* lbuf = base + 1024;                    // 10240
    int t = threadIdx.x;                        // 0..255

    ssm[t] = (t < KBUCK) ? btail[t] : 0;
    lcnt[t] = 0; lcnt[t + 256] = 0;
    __syncthreads();
    for (int s = 1; s < 256; s <<= 1) {         // inclusive scan of btail
        int a = (t >= s) ? ssm[t - s] : 0;
        __syncthreads();
        ssm[t] += a;
        __syncthreads();
    }
    int segstart = (b == 0) ? 0 : ssm[b - 1];
    int n = btail[b];
    const int* src = bscr + b * BSTRIDE;
    for (int i = t; i < n; i += 256)
        atomicAdd(&lcnt[src[i] >> 17], 1);
    __syncthreads();

    int c0 = lcnt[2 * t], c1 = lcnt[2 * t + 1];
    int cs = c0 + c1;
    lpre[t] = cs; __syncthreads();
    for (int s = 1; s < 256; s <<= 1) {         // inclusive scan of pair sums
        int a = (t >= s) ? lpre[t - s] : 0;
        __syncthreads();
        lpre[t] += a;
        __syncthreads();
    }
    int exclp = lpre[t] - cs;                   // exclusive prefix of dst 2t
    int excl0 = exclp, excl1 = exclp + c0;

    int v0 = (b << WSHIFT) + 2 * t;
    if (v0 < N_NODES) {
        row_ptr[v0] = segstart + excl0;
        dinv[v0] = rsqrtf((float)(c0 + 1));     // +1 self loop
    }
    if (v0 + 1 < N_NODES) {
        row_ptr[v0 + 1] = segstart + excl1;
        dinv[v0 + 1] = rsqrtf((float)(c1 + 1));
    }
    if (b == KBUCK - 1 && t == 0) row_ptr[N_NODES] = N_EDGES;
    lcnt[2 * t] = excl0;                        // reuse as cursors (own pair)
    lcnt[2 * t + 1] = excl1;
    __syncthreads();

    if (n <= LCAP) {
        for (int i = t; i < n; i += 256) {
            int e = src[i];
            int pos = atomicAdd(&lcnt[e >> 17], 1);
            lbuf[pos] = e & 0x1FFFF;
        }
        __syncthreads();
        for (int i = t; i < n; i += 256)
            col[segstart + i] = lbuf[i];
    } else {                                    // safety fallback (never for this dist)
        for (int i = t; i < n; i += 256) {
            int e = src[i];
            int pos = atomicAdd(&lcnt[e >> 17], 1);
            col[segstart + pos] = e & 0x1FFFF;
        }
    }
}

// ---------------- fused encoder body: x -> h1 -> h128 -> z0 (UNscaled) ------
__device__ __forceinline__ void encfull_body(unsigned char* sm, int bid,
    const float* __restrict__ x,
    const unsigned short* __restrict__ Wp1, const float* __restrict__ b1,
    const unsigned short* __restrict__ Wp2, const float* __restrict__ b2,
    const unsigned short* __restrict__ Wp0,
    _Float16* __restrict__ yout, int M)
{
    unsigned short* smem = (unsigned short*)sm;            // 50176 B used
    unsigned short (*As)[40]   = (unsigned short(*)[40])smem;      // 5120 B
    unsigned short* Wls1       = smem + 2560;                      // 16384 B
    unsigned short (*H1)[264]  = (unsigned short(*)[264])smem;     // 33792 B
    unsigned short (*H128)[136]= (unsigned short(*)[136])smem;     // 17408 B
    unsigned short* Wls2       = smem + 16896;                     // region1: 16384 B
    unsigned short* W0s        = smem + 16896;                     // region1 alias: 8192 B

    int t = threadIdx.x, wave = t >> 6, lane = t & 63;
    int m0 = bid * 64;
    int cb = lane & 15, rq = lane >> 4;

    {   // stage A: 64 rows x 32 k, fp32 -> bf16 (8 floats/thread)
        int row = t >> 2, seg = t & 3;
        int gr = m0 + row;
        float4 a = make_float4(0.f, 0.f, 0.f, 0.f), b = a;
        if (gr < M) {
            a = *(const float4*)&x[(size_t)gr * 32 + seg * 8];
            b = *(const float4*)&x[(size_t)gr * 32 + seg * 8 + 4];
        }
        unsigned short tmp[8] = { f2bf(a.x), f2bf(a.y), f2bf(a.z), f2bf(a.w),
                                  f2bf(b.x), f2bf(b.y), f2bf(b.z), f2bf(b.w) };
        *(uint4*)&As[row][seg * 8] = *(uint4*)tmp;
    }
    #pragma unroll
    for (int j = 0; j < 4; ++j)
        ((uint4*)Wls1)[t + j * 256] = ((const uint4*)Wp1)[t + j * 256];
    __syncthreads();

    // ---- stage1 MFMA: 16 ntiles, K=32 single step ----
    short8_t af1 = *(const short8_t*)&As[wave * 16 + cb][rq * 8];
    f32x4 acc[16];
    #pragma unroll
    for (int nt = 0; nt < 16; ++nt) {
        short8_t bf = *(const short8_t*)&Wls1[(nt * 64 + lane) * 8];
        acc[nt] = __builtin_amdgcn_mfma_f32_16x16x32_bf16(af1, bf, (f32x4){0.f, 0.f, 0.f, 0.f}, 0, 0, 0);
    }
    __syncthreads();                            // As/Wls1 reads done; region0 -> H1

    #pragma unroll
    for (int nt = 0; nt < 16; ++nt) {
        int col = nt * 16 + cb;
        float bv = b1[col];
        #pragma unroll
        for (int r = 0; r < 4; ++r)
            H1[wave * 16 + rq * 4 + r][col] = f2bf(fmaxf(acc[nt][r] + bv, 0.f));
    }

    // ---- stage2: enc2 over 4 K-chunks of 64 ----
    f32x4 acc2[8];
    #pragma unroll
    for (int nt = 0; nt < 8; ++nt) acc2[nt] = (f32x4){0.f, 0.f, 0.f, 0.f};
    for (int ch = 0; ch < 4; ++ch) {
        #pragma unroll
        for (int j = 0; j < 4; ++j)
            ((uint4*)Wls2)[t + j * 256] = ((const uint4*)(Wp2 + (size_t)ch * 8192))[t + j * 256];
        __syncthreads();                        // also orders H1 writes (ch==0)
        #pragma unroll
        for (int ks = 0; ks < 2; ++ks) {
            short8_t af = *(const short8_t*)&H1[wave * 16 + cb][ch * 64 + ks * 32 + rq * 8];
            #pragma unroll
            for (int nt = 0; nt < 8; ++nt) {
                short8_t bf = *(const short8_t*)&Wls2[((nt * 2 + ks) * 64 + lane) * 8];
                acc2[nt] = __builtin_amdgcn_mfma_f32_16x16x32_bf16(af, bf, acc2[nt], 0, 0, 0);
            }
        }
        __syncthreads();                        // before next chunk overwrites Wls2
    }

    // ---- h128 -> LDS (overwrites H1 region; last sync above ordered reads) --
    #pragma unroll
    for (int nt = 0; nt < 8; ++nt) {
        int col = nt * 16 + cb;
        float bv = b2[col];
        #pragma unroll
        for (int r = 0; r < 4; ++r)
            H128[wave * 16 + rq * 4 + r][col] = f2bf(fmaxf(acc2[nt][r] + bv, 0.f));
    }
    // stage W0 (8192 us = 512 uint4; overwrites Wls2 -- ordered by loop-exit sync)
    ((uint4*)W0s)[t]       = ((const uint4*)Wp0)[t];
    ((uint4*)W0s)[t + 256] = ((const uint4*)Wp0)[t + 256];
    __syncthreads();

    // ---- stage3: conv0, K=128 (2 chunks), NT16=4 ----
    f32x4 acc3[4];
    #pragma unroll
    for (int nt = 0; nt < 4; ++nt) acc3[nt] = (f32x4){0.f, 0.f, 0.f, 0.f};
    #pragma unroll
    for (int ch = 0; ch < 2; ++ch) {
        #pragma unroll
        for (int ks = 0; ks < 2; ++ks) {
            short8_t af = *(const short8_t*)&H128[wave * 16 + cb][ch * 64 + ks * 32 + rq * 8];
            #pragma unroll
            for (int nt = 0; nt < 4; ++nt) {
                short8_t bf = *(const short8_t*)&W0s[(((ch * 4 + nt) * 2 + ks) * 64 + lane) * 8];
                acc3[nt] = __builtin_amdgcn_mfma_f32_16x16x32_bf16(af, bf, acc3[nt], 0, 0, 0);
            }
        }
    }

    // z0 = xw0 (NO dinv here -- applied per-edge in aggcv0)
    #pragma unroll
    for (int nt = 0; nt < 4; ++nt) {
        int col = nt * 16 + cb;
        #pragma unroll
        for (int r = 0; r < 4; ++r) {
            int gr = m0 + wave * 16 + rq * 4 + r;
            if (gr < M) yout[(size_t)gr * 64 + col] = (_Float16)(acc3[nt][r]);
        }
    }
}

// ---- D3: fill_place (blocks < KBUCK) || encoder (the rest), 256 threads ----
__global__ __launch_bounds__(256, 3) void mega_place_enc(
    const int* __restrict__ btail, const int* __restrict__ bscr,
    int* __restrict__ row_ptr, float* __restrict__ dinv, int* __restrict__ col,
    const float* __restrict__ x,
    const unsigned short* __restrict__ Wp1, const float* __restrict__ b1,
    const unsigned short* __restrict__ Wp2, const float* __restrict__ b2,
    const unsigned short* __restrict__ Wp0,
    _Float16* __restrict__ yout)
{
    __shared__ __align__(16) unsigned char sm[50176];   // union: place 45056 / enc 50176
    if (blockIdx.x < KBUCK)
        fill_place_body256(sm, blockIdx.x, btail, bscr, row_ptr, dinv, col);
    else
        encfull_body(sm, blockIdx.x - KBUCK, x, Wp1, b1, Wp2, b2, Wp0, yout, N_NODES);
}

// ---------------- fused agg + next-layer transform (aggcv) ------------------
// Per block: 32 nodes. Phase 1 = CSR gather epilogue; h (f16 residual state)
// -> HBM, bf16 rows -> LDS. Phase 2 = 32x64 @ 64x64 transform (4 MFMAs/wave),
// y_next = (h@W)*dinv -> f16 out. EDGE_DINV: input rows are UNscaled z (layer
// 0); multiply each gathered row by dinv[u] (L2-resident lookup, fma).
// Requires exact grid: N_NODES/32 blocks (100000 = 3125*32, no tail).
template<bool RESIDUAL, bool EDGE_DINV>
__device__ __forceinline__ void aggcv_body(
    const uint4* __restrict__ y4, const int* __restrict__ row_ptr, const int* __restrict__ col,
    const float* __restrict__ dinv, const float* __restrict__ bias,
    const unsigned short* __restrict__ Wp,     // swizzled bf16 64x64 (wprep_one<64,64>)
    _Float16* __restrict__ h,                  // f16 residual state [N,64] (in/out)
    _Float16* __restrict__ yout)               // f16 [N,64] next-layer y
{
    __shared__ __align__(16) unsigned short Ws[4096];    // 8 KB  B-fragments
    __shared__ __align__(16) unsigned short Hs[32][72];  // 4.6 KB bf16 rows (stride 144B)
    __shared__ float Dv[32];

    int t = threadIdx.x;
    ((uint4*)Ws)[t]       = ((const uint4*)Wp)[t];       // 512 uint4 cooperative
    ((uint4*)Ws)[t + 256] = ((const uint4*)Wp)[t + 256];

    int n  = t >> 3;                   // local node 0..31
    int sl = t & 7;
    int v  = blockIdx.x * 32 + n;      // always < N_NODES (exact grid)

    float dv = dinv[v];

    // ---- phase 1: gather ----
    float s[8];
    {
        uint4 a = y4[(size_t)v * 8 + sl];              // self loop
        float2 g;
        float w = EDGE_DINV ? dv : 1.0f;               // self row scaled by dinv[v]
        if (EDGE_DINV) {
            g = up16(a.x); s[0] = w * g.x; s[1] = w * g.y;  g = up16(a.y); s[2] = w * g.x; s[3] = w * g.y;
            g = up16(a.z); s[4] = w * g.x; s[5] = w * g.y;  g = up16(a.w); s[6] = w * g.x; s[7] = w * g.y;
        } else {
            g = up16(a.x); s[0] = g.x; s[1] = g.y;  g = up16(a.y); s[2] = g.x; s[3] = g.y;
            g = up16(a.z); s[4] = g.x; s[5] = g.y;  g = up16(a.w); s[6] = g.x; s[7] = g.y;
        }
    }
    auto accrow = [&](uint4 f, float w) {
        float2 g;
        if (EDGE_DINV) {
            g = up16(f.x); s[0] += w * g.x; s[1] += w * g.y;  g = up16(f.y); s[2] += w * g.x; s[3] += w * g.y;
            g = up16(f.z); s[4] += w * g.x; s[5] += w * g.y;  g = up16(f.w); s[6] += w * g.x; s[7] += w * g.y;
        } else {
            g = up16(f.x); s[0] += g.x; s[1] += g.y;  g = up16(f.y); s[2] += g.x; s[3] += g.y;
            g = up16(f.z); s[4] += g.x; s[5] += g.y;  g = up16(f.w); s[6] += g.x; s[7] += g.y;
        }
    };

    int rs = row_ptr[v], re = row_ptr[v + 1];
    int i = rs;
    for (; i + 7 < re; i += 8) {                // 8 outstanding 16B loads/lane
        int u0 = col[i],     u1 = col[i + 1], u2 = col[i + 2], u3 = col[i + 3];
        int u4 = col[i + 4], u5 = col[i + 5], u6 = col[i + 6], u7 = col[i + 7];
        float d0 = EDGE_DINV ? dinv[u0] : 1.0f, d1 = EDGE_DINV ? dinv[u1] : 1.0f;
        float d2 = EDGE_DINV ? dinv[u2] : 1.0f, d3 = EDGE_DINV ? dinv[u3] : 1.0f;
        float d4 = EDGE_DINV ? dinv[u4] : 1.0f, d5 = EDGE_DINV ? dinv[u5] : 1.0f;
        float d6 = EDGE_DINV ? dinv[u6] : 1.0f, d7 = EDGE_DINV ? dinv[u7] : 1.0f;
        uint4 f0 = y4[(size_t)u0 * 8 + sl];
        uint4 f1 = y4[(size_t)u1 * 8 + sl];
        uint4 f2 = y4[(size_t)u2 * 8 + sl];
        uint4 f3 = y4[(size_t)u3 * 8 + sl];
        uint4 f4 = y4[(size_t)u4 * 8 + sl];
        uint4 f5 = y4[(size_t)u5 * 8 + sl];
        uint4 f6 = y4[(size_t)u6 * 8 + sl];
        uint4 f7 = y4[(size_t)u7 * 8 + sl];
        accrow(f0, d0); accrow(f1, d1); accrow(f2, d2); accrow(f3, d3);
        accrow(f4, d4); accrow(f5, d5); accrow(f6, d6); accrow(f7, d7);
    }
    for (; i + 3 < re; i += 4) {
        int u0 = col[i], u1 = col[i + 1], u2 = col[i + 2], u3 = col[i + 3];
        float d0 = EDGE_DINV ? dinv[u0] : 1.0f, d1 = EDGE_DINV ? dinv[u1] : 1.0f;
        float d2 = EDGE_DINV ? dinv[u2] : 1.0f, d3 = EDGE_DINV ? dinv[u3] : 1.0f;
        uint4 f0 = y4[(size_t)u0 * 8 + sl];
        uint4 f1 = y4[(size_t)u1 * 8 + sl];
        uint4 f2 = y4[(size_t)u2 * 8 + sl];
        uint4 f3 = y4[(size_t)u3 * 8 + sl];
        accrow(f0, d0); accrow(f1, d1); accrow(f2, d2); accrow(f3, d3);
    }
    for (; i < re; ++i) {
        int u = col[i];
        float d = EDGE_DINV ? dinv[u] : 1.0f;
        accrow(y4[(size_t)u * 8 + sl], d);
    }

    float4 ba = *(const float4*)&bias[sl * 8];
    float4 bb = *(const float4*)&bias[sl * 8 + 4];
    float v0 = fmaxf(dv * s[0] + ba.x, 0.f), v1 = fmaxf(dv * s[1] + ba.y, 0.f);
    float v2 = fmaxf(dv * s[2] + ba.z, 0.f), v3 = fmaxf(dv * s[3] + ba.w, 0.f);
    float v4 = fmaxf(dv * s[4] + bb.x, 0.f), v5 = fmaxf(dv * s[5] + bb.y, 0.f);
    float v6 = fmaxf(dv * s[6] + bb.z, 0.f), v7 = fmaxf(dv * s[7] + bb.w, 0.f);
    if (RESIDUAL) {
        uint4 hr = *(const uint4*)&h[(size_t)v * 64 + sl * 8];
        float2 g;
        g = up16(hr.x); v0 += g.x; v1 += g.y;  g = up16(hr.y); v2 += g.x; v3 += g.y;
        g = up16(hr.z); v4 += g.x; v5 += g.y;  g = up16(hr.w); v6 += g.x; v7 += g.y;
    }
    // f16 residual state for the next layer (in-place safe: own row)
    union { _Float16 hf[8]; uint4 u; } hp;
    hp.hf[0] = (_Float16)v0; hp.hf[1] = (_Float16)v1; hp.hf[2] = (_Float16)v2; hp.hf[3] = (_Float16)v3;
    hp.hf[4] = (_Float16)v4; hp.hf[5] = (_Float16)v5; hp.hf[6] = (_Float16)v6; hp.hf[7] = (_Float16)v7;
    *(uint4*)&h[(size_t)v * 64 + sl * 8] = hp.u;
    // bf16 row into LDS for the MFMA transform (from f32 registers)
    union { unsigned short us[8]; uint4 u; } hb;
    hb.us[0] = f2bf(v0); hb.us[1] = f2bf(v1); hb.us[2] = f2bf(v2); hb.us[3] = f2bf(v3);
    hb.us[4] = f2bf(v4); hb.us[5] = f2bf(v5); hb.us[6] = f2bf(v6); hb.us[7] = f2bf(v7);
    *(uint4*)&Hs[n][sl * 8] = hb.u;
    if (sl == 0) Dv[n] = dv;
    __syncthreads();    // orders Ws + Hs + Dv stores before phase-2 reads

    // ---- phase 2: y = (H @ W) * dinv, 8 output tiles over 4 waves ----
    int wave = t >> 6, lane = t & 63;
    int rt   = wave & 1;               // row tile (16 rows)
    int ct0  = (wave >> 1) * 2;        // first of 2 col tiles
    f32x4 acc0 = (f32x4){0.f, 0.f, 0.f, 0.f}, acc1 = acc0;
    #pragma unroll
    for (int ks = 0; ks < 2; ++ks) {
        short8_t af = *(const short8_t*)&Hs[rt * 16 + (lane & 15)][ks * 32 + (lane >> 4) * 8];
        short8_t b0 = *(const short8_t*)&Ws[((ct0 * 2 + ks) * 64 + lane) * 8];
        short8_t b1 = *(const short8_t*)&Ws[(((ct0 + 1) * 2 + ks) * 64 + lane) * 8];
        acc0 = __builtin_amdgcn_mfma_f32_16x16x32_bf16(af, b0, acc0, 0, 0, 0);
        acc1 = __builtin_amdgcn_mfma_f32_16x16x32_bf16(af, b1, acc1, 0, 0, 0);
    }
    int cb = lane & 15, rq = lane >> 4;
    #pragma unroll
    for (int r = 0; r < 4; ++r) {
        int row = rt * 16 + rq * 4 + r;
        float dv2 = Dv[row];
        size_t go = (size_t)(blockIdx.x * 32 + row) * 64;
        yout[go + ct0 * 16 + cb]       = (_Float16)(acc0[r] * dv2);
        yout[go + (ct0 + 1) * 16 + cb] = (_Float16)(acc1[r] * dv2);
    }
}

__global__ __launch_bounds__(256, 6) void aggcv0_kernel(
    const uint4* y, const int* rp, const int* col, const float* dinv, const float* b,
    const unsigned short* Wp, _Float16* h, _Float16* yout) {
    aggcv_body<false, true>(y, rp, col, dinv, b, Wp, h, yout);   // z0 input: per-edge dinv
}
__global__ __launch_bounds__(256, 6) void aggcv1_kernel(
    const uint4* y, const int* rp, const int* col, const float* dinv, const float* b,
    const unsigned short* Wp, _Float16* h, _Float16* yout) {
    aggcv_body<true, false>(y, rp, col, dinv, b, Wp, h, yout);
}

// ---------------- CSR aggregation, final layer (bf16 out for ep) ------------
__global__ __launch_bounds__(256, 6) void agg2_kernel(
    const uint4* __restrict__ y4, const int* __restrict__ row_ptr, const int* __restrict__ col,
    const float* __restrict__ dinv, const float* __restrict__ bias,
    const _Float16* __restrict__ hprev, uint4* __restrict__ hb4)
{
    int v  = blockIdx.x * 32 + (threadIdx.x >> 3);
    int sl = threadIdx.x & 7;
    if (v >= N_NODES) return;

    float s[8];
    {
        uint4 a = y4[(size_t)v * 8 + sl];              // self loop
        float2 g;
        g = up16(a.x); s[0] = g.x; s[1] = g.y;  g = up16(a.y); s[2] = g.x; s[3] = g.y;
        g = up16(a.z); s[4] = g.x; s[5] = g.y;  g = up16(a.w); s[6] = g.x; s[7] = g.y;
    }
    auto accrow = [&](uint4 f) {
        float2 g;
        g = up16(f.x); s[0] += g.x; s[1] += g.y;  g = up16(f.y); s[2] += g.x; s[3] += g.y;
        g = up16(f.z); s[4] += g.x; s[5] += g.y;  g = up16(f.w); s[6] += g.x; s[7] += g.y;
    };

    int rs = row_ptr[v], re = row_ptr[v + 1];
    int i = rs;
    for (; i + 7 < re; i += 8) {
        int u0 = col[i],     u1 = col[i + 1], u2 = col[i + 2], u3 = col[i + 3];
        int u4 = col[i + 4], u5 = col[i + 5], u6 = col[i + 6], u7 = col[i + 7];
        uint4 f0 = y4[(size_t)u0 * 8 + sl];
        uint4 f1 = y4[(size_t)u1 * 8 + sl];
        uint4 f2 = y4[(size_t)u2 * 8 + sl];
        uint4 f3 = y4[(size_t)u3 * 8 + sl];
        uint4 f4 = y4[(size_t)u4 * 8 + sl];
        uint4 f5 = y4[(size_t)u5 * 8 + sl];
        uint4 f6 = y4[(size_t)u6 * 8 + sl];
        uint4 f7 = y4[(size_t)u7 * 8 + sl];
        accrow(f0); accrow(f1); accrow(f2); accrow(f3);
        accrow(f4); accrow(f5); accrow(f6); accrow(f7);
    }
    for (; i + 3 < re; i += 4) {
        int u0 = col[i], u1 = col[i + 1], u2 = col[i + 2], u3 = col[i + 3];
        uint4 f0 = y4[(size_t)u0 * 8 + sl];
        uint4 f1 = y4[(size_t)u1 * 8 + sl];
        uint4 f2 = y4[(size_t)u2 * 8 + sl];
        uint4 f3 = y4[(size_t)u3 * 8 + sl];
        accrow(f0); accrow(f1); accrow(f2); accrow(f3);
    }
    for (; i < re; ++i) accrow(y4[(size_t)col[i] * 8 + sl]);

    float dv = dinv[v];
    float4 ba = *(const float4*)&bias[sl * 8];
    float4 bb = *(const float4*)&bias[sl * 8 + 4];
    float v0 = fmaxf(dv * s[0] + ba.x, 0.f), v1 = fmaxf(dv * s[1] + ba.y, 0.f);
    float v2 = fmaxf(dv * s[2] + ba.z, 0.f), v3 = fmaxf(dv * s[3] + ba.w, 0.f);
    float v4 = fmaxf(dv * s[4] + bb.x, 0.f), v5 = fmaxf(dv * s[5] + bb.y, 0.f);
    float v6 = fmaxf(dv * s[6] + bb.z, 0.f), v7 = fmaxf(dv * s[7] + bb.w, 0.f);
    {
        uint4 hr = *(const uint4*)&hprev[(size_t)v * 64 + sl * 8];
        float2 g;
        g = up16(hr.x); v0 += g.x; v1 += g.y;  g = up16(hr.y); v2 += g.x; v3 += g.y;
        g = up16(hr.z); v4 += g.x; v5 += g.y;  g = up16(hr.w); v6 += g.x; v7 += g.y;
    }
    uint4 p;
    p.x = (unsigned)f2bf(v0) | ((unsigned)f2bf(v1) << 16);
    p.y = (unsigned)f2bf(v2) | ((unsigned)f2bf(v3) << 16);
    p.z = (unsigned)f2bf(v4) | ((unsigned)f2bf(v5) << 16);
    p.w = (unsigned)f2bf(v6) | ((unsigned)f2bf(v7) << 16);
    hb4[(size_t)v * 8 + sl] = p;
}

// ---------------- fused edge predictor ----------------
__global__ __launch_bounds__(256, 4) void mfma_ep12(
    const unsigned short* __restrict__ A, const int* __restrict__ gidx,
    const unsigned short* __restrict__ Wp1, const float* __restrict__ b1,
    const unsigned short* __restrict__ Wp2, const float* __restrict__ b2,
    const float* __restrict__ w3, const float* __restrict__ b3,
    float* __restrict__ out, int M)
{
    __shared__ __align__(16) unsigned short smem[12800];    // 25600 B
    unsigned short (*As)[72] = (unsigned short(*)[72])smem;
    unsigned short* Wls = smem + 4608;

    int t = threadIdx.x, wave = t >> 6, lane = t & 63;
    int m0 = blockIdx.x * 64;
    int cb = lane & 15, rq = lane >> 4;

    f32x4 acc[8];
    #pragma unroll
    for (int nt = 0; nt < 8; ++nt) acc[nt] = (f32x4){0.f, 0.f, 0.f, 0.f};

    for (int ch = 0; ch < 2; ++ch) {
        #pragma unroll
        for (int j = 0; j < 2; ++j) {
            int idx = t + j * 256;
            int row = idx >> 3, seg = idx & 7;
            int gr = m0 + row;
            uint4 v = make_uint4(0u, 0u, 0u, 0u);
            if (gr < M) {
                int node = (ch == 0) ? gidx[gr] : gidx[N_EL + gr];
                v = *(const uint4*)(A + (size_t)node * 64 + seg * 8);
            }
            *(uint4*)&As[row][seg * 8] = v;
        }
        #pragma unroll
        for (int j = 0; j < 4; ++j) {
            int idx = t + j * 256;
            ((uint4*)Wls)[idx] = ((const uint4*)(Wp1 + (size_t)ch * 8192))[idx];
        }
        __syncthreads();

        #pragma unroll
        for (int ks = 0; ks < 2; ++ks) {
            short8_t af = *(const short8_t*)&As[wave * 16 + cb][ks * 32 + rq * 8];
            #pragma unroll
            for (int nt = 0; nt < 8; ++nt) {
                short8_t bf = *(const short8_t*)&Wls[((nt * 2 + ks) * 64 + lane) * 8];
                acc[nt] = __builtin_amdgcn_mfma_f32_16x16x32_bf16(af, bf, acc[nt], 0, 0, 0);
            }
        }
        __syncthreads();
    }

    // ---- stage 2 prep: e1 -> LDS (bf16), W2 -> LDS ----
    unsigned short (*E1)[136] = (unsigned short(*)[136])smem;
    unsigned short* W2s = smem + 8704;
    #pragma unroll
    for (int nt = 0; nt < 8; ++nt) {
        int col = nt * 16 + cb;
        float bv = b1[col];
        #pragma unroll
        for (int r = 0; r < 4; ++r) {
            int row = wave * 16 + rq * 4 + r;
            E1[row][col] = f2bf(fmaxf(acc[nt][r] + bv, 0.f));
        }
    }
    ((uint4*)W2s)[t]       = ((const uint4*)Wp2)[t];
    ((uint4*)W2s)[t + 256] = ((const uint4*)Wp2)[t + 256];
    __syncthreads();

    // ---- stage 2 MFMA: NT16=4, NCH=2 over the 128-wide e1 ----
    f32x4 acc2[4];
    #pragma unroll
    for (int nt = 0; nt < 4; ++nt) acc2[nt] = (f32x4){0.f, 0.f, 0.f, 0.f};
    #pragma unroll
    for (int ch = 0; ch < 2; ++ch) {
        #pragma unroll
        for (int ks = 0; ks < 2; ++ks) {
            short8_t af = *(const short8_t*)&E1[wave * 16 + cb][ch * 64 + ks * 32 + rq * 8];
            #pragma unroll
            for (int nt = 0; nt < 4; ++nt) {
                short8_t bf = *(const short8_t*)&W2s[(((ch * 4 + nt) * 2 + ks) * 64 + lane) * 8];
                acc2[nt] = __builtin_amdgcn_mfma_f32_16x16x32_bf16(af, bf, acc2[nt], 0, 0, 0);
            }
        }
    }

    // ---- epilogue: relu + dot(w3) + sigmoid ----
    float s0 = 0.f, s1 = 0.f, s2 = 0.f, s3 = 0.f;
    #pragma unroll
    for (int nt = 0; nt < 4; ++nt) {
        int col = nt * 16 + cb;
        float bv = b2[col], wv = w3[col];
        s0 += fmaxf(acc2[nt][0] + bv, 0.f) * wv;
        s1 += fmaxf(acc2[nt][1] + bv, 0.f) * wv;
        s2 += fmaxf(acc2[nt][2] + bv, 0.f) * wv;
        s3 += fmaxf(acc2[nt][3] + bv, 0.f) * wv;
    }
    #pragma unroll
    for (int off = 1; off < 16; off <<= 1) {
        s0 += __shfl_xor(s0, off);
        s1 += __shfl_xor(s1, off);
        s2 += __shfl_xor(s2, off);
        s3 += __shfl_xor(s3, off);
    }
    if (cb == 0) {
        int gr = m0 + wave * 16 + rq * 4;
        if (gr + 3 < M) {
            float bb = b3[0];
            float4 o;
            o.x = 1.f / (1.f + expf(-(s0 + bb)));
            o.y = 1.f / (1.f + expf(-(s1 + bb)));
            o.z = 1.f / (1.f + expf(-(s2 + bb)));
            o.w = 1.f / (1.f + expf(-(s3 + bb)));
            *(float4*)&out[gr] = o;
        }
    }
}

extern "C" void kernel_launch(void* const* d_in, const int* in_sizes, int n_in,
                              void* d_out, int out_size, void* d_ws, size_t ws_size,
                              hipStream_t stream) {
    const float* x       = (const float*)d_in[0];
    const int*   ei      = (const int*)d_in[1];
    const int*   eli     = (const int*)d_in[2];
    const float* enc_w1  = (const float*)d_in[3];
    const float* enc_b1  = (const float*)d_in[4];
    const float* enc_w2  = (const float*)d_in[5];
    const float* enc_b2  = (const float*)d_in[6];
    const float* conv_w0 = (const float*)d_in[7];
    const float* conv_b0 = (const float*)d_in[8];
    const float* conv_w1 = (const float*)d_in[9];
    const float* conv_b1 = (const float*)d_in[10];
    const float* conv_w2 = (const float*)d_in[11];
    const float* conv_b2 = (const float*)d_in[12];
    const float* ep_w1   = (const float*)d_in[13];
    const float* ep_b1   = (const float*)d_in[14];
    const float* ep_w2   = (const float*)d_in[15];
    const float* ep_b2   = (const float*)d_in[16];
    const float* ep_w3   = (const float*)d_in[17];
    const float* ep_b3   = (const float*)d_in[18];
    float* out = (float*)d_out;

    // ---- workspace layout (float offsets) ----
    float* fws = (float*)d_ws;
    _Float16* yb         = (_Float16*)fws;                       // f16 [100k,64] = 3.2M f
    _Float16* h16        = (_Float16*)(fws + 3200000);           // f16 [100k,64] residual state
    unsigned short* h64b = (unsigned short*)(fws + 9600000);     // bf16/f16 [100k,64] = 3.2M f
    int*   col     = (int*)(fws + 12800000);                     // 1.6M i
    int*   row_ptr = col + 1600000;                              // 100001 (padded)
    float* dinvp   = (float*)(row_ptr + 100032);
    unsigned short* w2p = (unsigned short*)(dinvp + 100000);     // enc_w2: 32768 us
    unsigned short* w0p = w2p + 32768;                           // conv_w0: 8192 us
    unsigned short* w1p = w0p + 8192;                            // ep_w1: 16384 us
    unsigned short* wp2 = w1p + 16384;                           // ep_w2: 8192 us
    unsigned short* w1e = wp2 + 8192;                            // enc_w1: 8192 us
    unsigned short* wc1p = w1e + 8192;                           // conv_w1: 4096 us
    unsigned short* wc2p = wc1p + 4096;                          // conv_w2: 4096 us
    int*   btail   = (int*)(wc2p + 4096);                        // 196 i (+pad to 256)
    int*   bscr    = btail + 256;                                // 196*12288 = 2.41M i

    // y double-buffer: h64b region is free until agg2 writes the final hb.
    _Float16* yb2 = (_Float16*)h64b;

    const int GBE = N_EL / 64;             // 3125
    const int GBA = N_NODES / 32;          // 3125 (exact: 100000 = 3125*32)

    // ---- D1: all weight swizzles + btail zero ----
    prep0<<<321, 256, 0, stream>>>(enc_w2, conv_w0, ep_w1, ep_w2, enc_w1, conv_w1, conv_w2,
                                   w2p, w0p, w1p, wp2, w1e, wc1p, wc2p, btail);

    // ---- D2: CSR partition (standalone, ~13us) ----
    fill_part<<<PART_NB, 256, 0, stream>>>(ei, btail, bscr);

    // ---- D3: CSR finalize (256-thr) || encoder->z0 (proven 256-thr) ----
    mega_place_enc<<<KBUCK + ENC_NB, 256, 0, stream>>>(btail, bscr, row_ptr, dinvp, col,
        x, w1e, enc_b1, w2p, enc_b2, w0p, yb);

    // ---- D4: layer 1: agg(dinv.*z0) -> h0 (f16) ; y1 = (h0@W1)*dinv fused ----
    aggcv0_kernel<<<GBA, 256, 0, stream>>>((const uint4*)yb, row_ptr, col, dinvp, conv_b0,
                                           wc1p, h16, yb2);
    // ---- D5: layer 2: agg(y1) -> h1 (residual, f16) ; y2 = (h1@W2)*dinv fused ----
    aggcv1_kernel<<<GBA, 256, 0, stream>>>((const uint4*)yb2, row_ptr, col, dinvp, conv_b1,
                                           wc2p, h16, yb);
    // ---- D6: layer 3: agg(y2) -> h2 (residual), bf16 out for ep ----
    agg2_kernel<<<GBA, 256, 0, stream>>>((const uint4*)yb, row_ptr, col, dinvp, conv_b2,
                                         h16, (uint4*)h64b);

    // ---- D7: edge predictor: ep1+ep2+ep3 fused, e1 lives in LDS ----
    mfma_ep12<<<GBE, 256, 0, stream>>>(h64b, eli, w1p, ep_b1, wp2, ep_b2, ep_w3, ep_b3, out, N_EL);
}

// Round 10
// 272.087 us; speedup vs baseline: 1.0162x; 1.0162x over previous
//
#include <hip/hip_runtime.h>
#include <math.h>

// ---------------------------------------------------------------------------
// EmergencyGNNEnhanced: encoder (32->256->128) -> 3x GCN (->64) -> edge MLP.
// CSR built on-device each call. agg[v] = dinv[v]*(sum_{u->v} y[u] + y[v]).
//
// R26 = revert to R24 (best measured 274.6us). R25's place||enc overlap was
// neutral: mega dispatch time is set by the encoder's 1563 blocks (2+ rounds
// at 3 blk/CU); fill blocks ride inside round 1 either way, and the split
// fill_part added a serial 13us + launch gap. Structural floors reached:
//  - aggs: FETCH = 8-XCD x 12.8MB table replication, ~2.9TB/s LLC random-line
//    rate (ILP/TLP/locality/NT all tested flat; only byte cuts moved it).
//  - front-end: 3 blk/CU occupancy-round quantization of >50KB-LDS bodies.
//  - precision: y/h f16, MFMA bf16; absmax pinned at 2^-9.
// ---------------------------------------------------------------------------

#define N_NODES 100000
#define N_EDGES 1600000
#define N_EL    200000

#define KBUCK   196          // ceil(100000/512) windows of 512 nodes
#define WSHIFT  9
#define WMASK   511
#define BCAP    64           // LDS entries/bucket in pass A (chunk avg ~16)
#define BSTRIDE 12288        // scratch ints per bucket (seglen ~8.2k avg)
#define PART_NB 512
#define CHUNK   3125         // ceil(N_EDGES / PART_NB)
#define LCAP    10240        // pass-B LDS staging (seglen max ~8.8k)
#define ENC_NB  1563         // ceil(100000/64)

typedef __attribute__((ext_vector_type(8))) short short8_t;
typedef __attribute__((ext_vector_type(4))) float f32x4;

__device__ __forceinline__ unsigned short f2bf(float f) {
    unsigned u = __float_as_uint(f);
    unsigned r = u + 0x7FFFu + ((u >> 16) & 1u);   // RNE
    return (unsigned short)(r >> 16);
}

__device__ __forceinline__ float2 up16(unsigned u) {
    union { unsigned v; _Float16 h[2]; } c; c.v = u;
    return make_float2((float)c.h[0], (float)c.h[1]);
}

// ---------------- weight swizzle: fp32 W[K][N] -> bf16 B-fragment order -----
template<int KTOT, int NTOT>
__device__ __forceinline__ void wprep_one(const float* __restrict__ W, unsigned short* __restrict__ Wp, int flat) {
    if (flat >= KTOT * NTOT) return;
    int j = flat & 7, lane = (flat >> 3) & 63, kstep = (flat >> 9) & 1;
    int rest = flat >> 10;
    int ntile = rest % (NTOT / 16), chunk = rest / (NTOT / 16);
    int k = chunk * 64 + kstep * 32 + (lane >> 4) * 8 + j;
    int n = ntile * 16 + (lane & 15);
    Wp[flat] = f2bf(W[(size_t)k * NTOT + n]);
}

// K=32 variant (single k-step) for enc_w1 [32 x 256]
__device__ __forceinline__ void wprep32_one(const float* __restrict__ W, unsigned short* __restrict__ Wp, int flat) {
    if (flat >= 32 * 256) return;
    int j = flat & 7, lane = (flat >> 3) & 63, ntile = flat >> 9;   // 0..15
    int k = (lane >> 4) * 8 + j;
    int n = ntile * 16 + (lane & 15);
    Wp[flat] = f2bf(W[(size_t)k * 256 + n]);
}

// ---- prep0: ALL weight swizzles (blocks 0..319) + btail zero (block 320) ---
__global__ __launch_bounds__(256) void prep0(
    const float* w2, const float* w0, const float* w1, const float* wpp2, const float* w1e,
    const float* wc1, const float* wc2,
    unsigned short* p2, unsigned short* p0, unsigned short* p1, unsigned short* pp2,
    unsigned short* p1e, unsigned short* pc1, unsigned short* pc2,
    int* btail)
{
    int blk = blockIdx.x, t = threadIdx.x;
    if      (blk < 128) wprep_one<256, 128>(w2,  p2,  blk * 256 + t);
    else if (blk < 160) wprep_one<128,  64>(w0,  p0,  (blk - 128) * 256 + t);
    else if (blk < 224) wprep_one<128, 128>(w1,  p1,  (blk - 160) * 256 + t);
    else if (blk < 256) wprep_one<128,  64>(wpp2, pp2, (blk - 224) * 256 + t);
    else if (blk < 288) wprep32_one(w1e, p1e, (blk - 256) * 256 + t);
    else if (blk < 304) wprep_one< 64,  64>(wc1, pc1, (blk - 288) * 256 + t);
    else if (blk < 320) wprep_one< 64,  64>(wc2, pc2, (blk - 304) * 256 + t);
    else                btail[t] = 0;           // block 320: zero btail[0..255]
}

// ---------------- fill pass A body (dst-window partition) -------------------
__device__ __forceinline__ void fill_part_body(unsigned char* sm,
                                               const int* __restrict__ ei,
                                               int* __restrict__ btail, int* __restrict__ bscr)
{
    int* base = (int*)sm;
    int (*lbuf)[BCAP] = (int(*)[BCAP])base;     // 12544 ints = 50176 B
    int* lcnt  = base + 12544;                  // 196
    int* offs  = base + 12740;                  // 197
    int* gbase = base + 12937;                  // 196
    int* sscan = base + 13133;                  // 256 -> end 53556 B
    int t = threadIdx.x;

    for (int i = t; i < KBUCK; i += 256) lcnt[i] = 0;
    __syncthreads();

    int e0   = blockIdx.x * CHUNK;
    int eend = e0 + CHUNK; if (eend > N_EDGES) eend = N_EDGES;
    for (int e = e0 + t; e < eend; e += 256) {
        int s = __builtin_nontemporal_load(ei + e);
        int d = __builtin_nontemporal_load(ei + N_EDGES + e);
        int b = d >> WSHIFT;
        int entry = ((d & WMASK) << 17) | s;
        int pos = atomicAdd(&lcnt[b], 1);
        if (pos < BCAP) lbuf[b][pos] = entry;
        else {                                  // statistical-skew spill (rare)
            int p = atomicAdd(&btail[b], 1);
            bscr[b * BSTRIDE + p] = entry;
        }
    }
    __syncthreads();

    int myc = 0;
    if (t < KBUCK) {
        myc = lcnt[t]; if (myc > BCAP) myc = BCAP;
        lcnt[t] = myc;
        gbase[t] = atomicAdd(&btail[t], myc);
    }
    // parallel inclusive scan of clamped counts -> offs[1..KBUCK]
    sscan[t] = (t < KBUCK) ? myc : 0;
    __syncthreads();
    for (int s = 1; s < 256; s <<= 1) {
        int a = (t >= s) ? sscan[t - s] : 0;
        __syncthreads();
        sscan[t] += a;
        __syncthreads();
    }
    if (t < KBUCK) offs[t + 1] = sscan[t];
    if (t == 0) offs[0] = 0;
    __syncthreads();

    int T = offs[KBUCK];
    for (int i = t; i < T; i += 256) {
        int loB = 0, hiB = KBUCK;               // binary search bucket
        while (hiB - loB > 1) { int mid = (loB + hiB) >> 1; if (offs[mid] <= i) loB = mid; else hiB = mid; }
        int j = i - offs[loB];
        bscr[loB * BSTRIDE + gbase[loB] + j] = lbuf[loB][j];
    }
}

// ---------------- fused encoder body: x -> h1 -> h128 -> z0 (UNscaled) ------
__device__ __forceinline__ void encfull_body(unsigned char* sm, int bid,
    const float* __restrict__ x,
    const unsigned short* __restrict__ Wp1, const float* __restrict__ b1,
    const unsigned short* __restrict__ Wp2, const float* __restrict__ b2,
    const unsigned short* __restrict__ Wp0,
    _Float16* __restrict__ yout, int M)
{
    unsigned short* smem = (unsigned short*)sm;            // 50176 B used
    unsigned short (*As)[40]   = (unsigned short(*)[40])smem;      // 5120 B
    unsigned short* Wls1       = smem + 2560;                      // 16384 B
    unsigned short (*H1)[264]  = (unsigned short(*)[264])smem;     // 33792 B
    unsigned short (*H128)[136]= (unsigned short(*)[136])smem;     // 17408 B
    unsigned short* Wls2       = smem + 16896;                     // region1: 16384 B
    unsigned short* W0s        = smem + 16896;                     // region1 alias: 8192 B

    int t = threadIdx.x, wave = t >> 6, lane = t & 63;
    int m0 = bid * 64;
    int cb = lane & 15, rq = lane >> 4;

    {   // stage A: 64 rows x 32 k, fp32 -> bf16 (8 floats/thread)
        int row = t >> 2, seg = t & 3;
        int gr = m0 + row;
        float4 a = make_float4(0.f, 0.f, 0.f, 0.f), b = a;
        if (gr < M) {
            a = *(const float4*)&x[(size_t)gr * 32 + seg * 8];
            b = *(const float4*)&x[(size_t)gr * 32 + seg * 8 + 4];
        }
        unsigned short tmp[8] = { f2bf(a.x), f2bf(a.y), f2bf(a.z), f2bf(a.w),
                                  f2bf(b.x), f2bf(b.y), f2bf(b.z), f2bf(b.w) };
        *(uint4*)&As[row][seg * 8] = *(uint4*)tmp;
    }
    #pragma unroll
    for (int j = 0; j < 4; ++j)
        ((uint4*)Wls1)[t + j * 256] = ((const uint4*)Wp1)[t + j * 256];
    __syncthreads();

    // ---- stage1 MFMA: 16 ntiles, K=32 single step ----
    short8_t af1 = *(const short8_t*)&As[wave * 16 + cb][rq * 8];
    f32x4 acc[16];
    #pragma unroll
    for (int nt = 0; nt < 16; ++nt) {
        short8_t bf = *(const short8_t*)&Wls1[(nt * 64 + lane) * 8];
        acc[nt] = __builtin_amdgcn_mfma_f32_16x16x32_bf16(af1, bf, (f32x4){0.f, 0.f, 0.f, 0.f}, 0, 0, 0);
    }
    __syncthreads();                            // As/Wls1 reads done; region0 -> H1

    #pragma unroll
    for (int nt = 0; nt < 16; ++nt) {
        int col = nt * 16 + cb;
        float bv = b1[col];
        #pragma unroll
        for (int r = 0; r < 4; ++r)
            H1[wave * 16 + rq * 4 + r][col] = f2bf(fmaxf(acc[nt][r] + bv, 0.f));
    }

    // ---- stage2: enc2 over 4 K-chunks of 64 ----
    f32x4 acc2[8];
    #pragma unroll
    for (int nt = 0; nt < 8; ++nt) acc2[nt] = (f32x4){0.f, 0.f, 0.f, 0.f};
    for (int ch = 0; ch < 4; ++ch) {
        #pragma unroll
        for (int j = 0; j < 4; ++j)
            ((uint4*)Wls2)[t + j * 256] = ((const uint4*)(Wp2 + (size_t)ch * 8192))[t + j * 256];
        __syncthreads();                        // also orders H1 writes (ch==0)
        #pragma unroll
        for (int ks = 0; ks < 2; ++ks) {
            short8_t af = *(const short8_t*)&H1[wave * 16 + cb][ch * 64 + ks * 32 + rq * 8];
            #pragma unroll
            for (int nt = 0; nt < 8; ++nt) {
                short8_t bf = *(const short8_t*)&Wls2[((nt * 2 + ks) * 64 + lane) * 8];
                acc2[nt] = __builtin_amdgcn_mfma_f32_16x16x32_bf16(af, bf, acc2[nt], 0, 0, 0);
            }
        }
        __syncthreads();                        // before next chunk overwrites Wls2
    }

    // ---- h128 -> LDS (overwrites H1 region; last sync above ordered reads) --
    #pragma unroll
    for (int nt = 0; nt < 8; ++nt) {
        int col = nt * 16 + cb;
        float bv = b2[col];
        #pragma unroll
        for (int r = 0; r < 4; ++r)
            H128[wave * 16 + rq * 4 + r][col] = f2bf(fmaxf(acc2[nt][r] + bv, 0.f));
    }
    // stage W0 (8192 us = 512 uint4; overwrites Wls2 -- ordered by loop-exit sync)
    ((uint4*)W0s)[t]       = ((const uint4*)Wp0)[t];
    ((uint4*)W0s)[t + 256] = ((const uint4*)Wp0)[t + 256];
    __syncthreads();

    // ---- stage3: conv0, K=128 (2 chunks), NT16=4 ----
    f32x4 acc3[4];
    #pragma unroll
    for (int nt = 0; nt < 4; ++nt) acc3[nt] = (f32x4){0.f, 0.f, 0.f, 0.f};
    #pragma unroll
    for (int ch = 0; ch < 2; ++ch) {
        #pragma unroll
        for (int ks = 0; ks < 2; ++ks) {
            short8_t af = *(const short8_t*)&H128[wave * 16 + cb][ch * 64 + ks * 32 + rq * 8];
            #pragma unroll
            for (int nt = 0; nt < 4; ++nt) {
                short8_t bf = *(const short8_t*)&W0s[(((ch * 4 + nt) * 2 + ks) * 64 + lane) * 8];
                acc3[nt] = __builtin_amdgcn_mfma_f32_16x16x32_bf16(af, bf, acc3[nt], 0, 0, 0);
            }
        }
    }

    // z0 = xw0 (NO dinv here -- applied per-edge in aggcv0)
    #pragma unroll
    for (int nt = 0; nt < 4; ++nt) {
        int col = nt * 16 + cb;
        #pragma unroll
        for (int r = 0; r < 4; ++r) {
            int gr = m0 + wave * 16 + rq * 4 + r;
            if (gr < M) yout[(size_t)gr * 64 + col] = (_Float16)(acc3[nt][r]);
        }
    }
}

// ---- mega dispatch: fill_part (blocks < PART_NB) || encoder (the rest) -----
__global__ __launch_bounds__(256, 3) void mega_fill_enc(
    const int* __restrict__ ei, int* __restrict__ btail, int* __restrict__ bscr,
    const float* __restrict__ x,
    const unsigned short* __restrict__ Wp1, const float* __restrict__ b1,
    const unsigned short* __restrict__ Wp2, const float* __restrict__ b2,
    const unsigned short* __restrict__ Wp0,
    _Float16* __restrict__ yout)
{
    __shared__ __align__(16) unsigned char sm[53568];   // union: fill 53556 / enc 50176
    if (blockIdx.x < PART_NB)
        fill_part_body(sm, ei, btail, bscr);
    else
        encfull_body(sm, blockIdx.x - PART_NB, x, Wp1, b1, Wp2, b2, Wp0, yout, N_NODES);
}

// ---- fill_place: btail prefix + hist + local scan + row_ptr/dinv + scatter ----
// 196 blocks x 512 threads; each block owns a 512-node dst window (~8.2k edges).
__global__ __launch_bounds__(512) void fill_place(const int* __restrict__ btail,
                                                  const int* __restrict__ bscr,
                                                  int* __restrict__ row_ptr, float* __restrict__ dinv,
                                                  int* __restrict__ col) {
    __shared__ int ssm[256];
    __shared__ int lcnt[512];
    __shared__ int lpre[512];
    __shared__ int lbuf[LCAP];                  // 40 KB
    int b = blockIdx.x, t = threadIdx.x;

    if (t < 256) ssm[t] = (t < KBUCK) ? btail[t] : 0;
    lcnt[t] = 0;
    __syncthreads();
    for (int s = 1; s < 256; s <<= 1) {         // inclusive scan of btail
        int a = 0;
        if (t < 256 && t >= s) a = ssm[t - s];
        __syncthreads();
        if (t < 256) ssm[t] += a;
        __syncthreads();
    }
    int segstart = (b == 0) ? 0 : ssm[b - 1];
    int n = btail[b];
    const int* src = bscr + b * BSTRIDE;
    for (int i = t; i < n; i += 512)
        atomicAdd(&lcnt[src[i] >> 17], 1);
    __syncthreads();

    int c = lcnt[t];
    lpre[t] = c; __syncthreads();
    for (int s = 1; s < 512; s <<= 1) {         // inclusive scan
        int a = (t >= s) ? lpre[t - s] : 0;
        __syncthreads();
        lpre[t] += a;
        __syncthreads();
    }
    int excl = lpre[t] - c;

    int v = (b << WSHIFT) + t;
    if (v < N_NODES) {
        row_ptr[v] = segstart + excl;
        dinv[v] = rsqrtf((float)(c + 1));       // +1 self loop
    }
    if (b == KBUCK - 1 && t == 0) row_ptr[N_NODES] = N_EDGES;
    lcnt[t] = excl;                             // reuse as cursor
    __syncthreads();

    if (n <= LCAP) {
        for (int i = t; i < n; i += 512) {
            int e = src[i];
            int pos = atomicAdd(&lcnt[e >> 17], 1);
            lbuf[pos] = e & 0x1FFFF;
        }
        __syncthreads();
        for (int i = t; i < n; i += 512)
            col[segstart + i] = lbuf[i];
    } else {                                    // safety fallback (never for this dist)
        for (int i = t; i < n; i += 512) {
            int e = src[i];
            int pos = atomicAdd(&lcnt[e >> 17], 1);
            col[segstart + pos] = e & 0x1FFFF;
        }
    }
}

// ---------------- fused agg + next-layer transform (aggcv) ------------------
// Per block: 32 nodes. Phase 1 = CSR gather epilogue; h (f16 residual state)
// -> HBM, bf16 rows -> LDS. Phase 2 = 32x64 @ 64x64 transform (4 MFMAs/wave),
// y_next = (h@W)*dinv -> f16 out. EDGE_DINV: input rows are UNscaled z (layer
// 0); multiply each gathered row by dinv[u] (L2-resident lookup, fma).
// Requires exact grid: N_NODES/32 blocks (100000 = 3125*32, no tail).
template<bool RESIDUAL, bool EDGE_DINV>
__device__ __forceinline__ void aggcv_body(
    const uint4* __restrict__ y4, const int* __restrict__ row_ptr, const int* __restrict__ col,
    const float* __restrict__ dinv, const float* __restrict__ bias,
    const unsigned short* __restrict__ Wp,     // swizzled bf16 64x64 (wprep_one<64,64>)
    _Float16* __restrict__ h,                  // f16 residual state [N,64] (in/out)
    _Float16* __restrict__ yout)               // f16 [N,64] next-layer y
{
    __shared__ __align__(16) unsigned short Ws[4096];    // 8 KB  B-fragments
    __shared__ __align__(16) unsigned short Hs[32][72];  // 4.6 KB bf16 rows (stride 144B)
    __shared__ float Dv[32];

    int t = threadIdx.x;
    ((uint4*)Ws)[t]       = ((const uint4*)Wp)[t];       // 512 uint4 cooperative
    ((uint4*)Ws)[t + 256] = ((const uint4*)Wp)[t + 256];

    int n  = t >> 3;                   // local node 0..31
    int sl = t & 7;
    int v  = blockIdx.x * 32 + n;      // always < N_NODES (exact grid)

    float dv = dinv[v];

    // ---- phase 1: gather ----
    float s[8];
    {
        uint4 a = y4[(size_t)v * 8 + sl];              // self loop
        float2 g;
        float w = EDGE_DINV ? dv : 1.0f;               // self row scaled by dinv[v]
        if (EDGE_DINV) {
            g = up16(a.x); s[0] = w * g.x; s[1] = w * g.y;  g = up16(a.y); s[2] = w * g.x; s[3] = w * g.y;
            g = up16(a.z); s[4] = w * g.x; s[5] = w * g.y;  g = up16(a.w); s[6] = w * g.x; s[7] = w * g.y;
        } else {
            g = up16(a.x); s[0] = g.x; s[1] = g.y;  g = up16(a.y); s[2] = g.x; s[3] = g.y;
            g = up16(a.z); s[4] = g.x; s[5] = g.y;  g = up16(a.w); s[6] = g.x; s[7] = g.y;
        }
    }
    auto accrow = [&](uint4 f, float w) {
        float2 g;
        if (EDGE_DINV) {
            g = up16(f.x); s[0] += w * g.x; s[1] += w * g.y;  g = up16(f.y); s[2] += w * g.x; s[3] += w * g.y;
            g = up16(f.z); s[4] += w * g.x; s[5] += w * g.y;  g = up16(f.w); s[6] += w * g.x; s[7] += w * g.y;
        } else {
            g = up16(f.x); s[0] += g.x; s[1] += g.y;  g = up16(f.y); s[2] += g.x; s[3] += g.y;
            g = up16(f.z); s[4] += g.x; s[5] += g.y;  g = up16(f.w); s[6] += g.x; s[7] += g.y;
        }
    };

    int rs = row_ptr[v], re = row_ptr[v + 1];
    int i = rs;
    for (; i + 7 < re; i += 8) {                // 8 outstanding 16B loads/lane
        int u0 = col[i],     u1 = col[i + 1], u2 = col[i + 2], u3 = col[i + 3];
        int u4 = col[i + 4], u5 = col[i + 5], u6 = col[i + 6], u7 = col[i + 7];
        float d0 = EDGE_DINV ? dinv[u0] : 1.0f, d1 = EDGE_DINV ? dinv[u1] : 1.0f;
        float d2 = EDGE_DINV ? dinv[u2] : 1.0f, d3 = EDGE_DINV ? dinv[u3] : 1.0f;
        float d4 = EDGE_DINV ? dinv[u4] : 1.0f, d5 = EDGE_DINV ? dinv[u5] : 1.0f;
        float d6 = EDGE_DINV ? dinv[u6] : 1.0f, d7 = EDGE_DINV ? dinv[u7] : 1.0f;
        uint4 f0 = y4[(size_t)u0 * 8 + sl];
        uint4 f1 = y4[(size_t)u1 * 8 + sl];
        uint4 f2 = y4[(size_t)u2 * 8 + sl];
        uint4 f3 = y4[(size_t)u3 * 8 + sl];
        uint4 f4 = y4[(size_t)u4 * 8 + sl];
        uint4 f5 = y4[(size_t)u5 * 8 + sl];
        uint4 f6 = y4[(size_t)u6 * 8 + sl];
        uint4 f7 = y4[(size_t)u7 * 8 + sl];
        accrow(f0, d0); accrow(f1, d1); accrow(f2, d2); accrow(f3, d3);
        accrow(f4, d4); accrow(f5, d5); accrow(f6, d6); accrow(f7, d7);
    }
    for (; i + 3 < re; i += 4) {
        int u0 = col[i], u1 = col[i + 1], u2 = col[i + 2], u3 = col[i + 3];
        float d0 = EDGE_DINV ? dinv[u0] : 1.0f, d1 = EDGE_DINV ? dinv[u1] : 1.0f;
        float d2 = EDGE_DINV ? dinv[u2] : 1.0f, d3 = EDGE_DINV ? dinv[u3] : 1.0f;
        uint4 f0 = y4[(size_t)u0 * 8 + sl];
        uint4 f1 = y4[(size_t)u1 * 8 + sl];
        uint4 f2 = y4[(size_t)u2 * 8 + sl];
        uint4 f3 = y4[(size_t)u3 * 8 + sl];
        accrow(f0, d0); accrow(f1, d1); accrow(f2, d2); accrow(f3, d3);
    }
    for (; i < re; ++i) {
        int u = col[i];
        float d = EDGE_DINV ? dinv[u] : 1.0f;
        accrow(y4[(size_t)u * 8 + sl], d);
    }

    float4 ba = *(const float4*)&bias[sl * 8];
    float4 bb = *(const float4*)&bias[sl * 8 + 4];
    float v0 = fmaxf(dv * s[0] + ba.x, 0.f), v1 = fmaxf(dv * s[1] + ba.y, 0.f);
    float v2 = fmaxf(dv * s[2] + ba.z, 0.f), v3 = fmaxf(dv * s[3] + ba.w, 0.f);
    float v4 = fmaxf(dv * s[4] + bb.x, 0.f), v5 = fmaxf(dv * s[5] + bb.y, 0.f);
    float v6 = fmaxf(dv * s[6] + bb.z, 0.f), v7 = fmaxf(dv * s[7] + bb.w, 0.f);
    if (RESIDUAL) {
        uint4 hr = *(const uint4*)&h[(size_t)v * 64 + sl * 8];
        float2 g;
        g = up16(hr.x); v0 += g.x; v1 += g.y;  g = up16(hr.y); v2 += g.x; v3 += g.y;
        g = up16(hr.z); v4 += g.x; v5 += g.y;  g = up16(hr.w); v6 += g.x; v7 += g.y;
    }
    // f16 residual state for the next layer (in-place safe: own row)
    union { _Float16 hf[8]; uint4 u; } hp;
    hp.hf[0] = (_Float16)v0; hp.hf[1] = (_Float16)v1; hp.hf[2] = (_Float16)v2; hp.hf[3] = (_Float16)v3;
    hp.hf[4] = (_Float16)v4; hp.hf[5] = (_Float16)v5; hp.hf[6] = (_Float16)v6; hp.hf[7] = (_Float16)v7;
    *(uint4*)&h[(size_t)v * 64 + sl * 8] = hp.u;
    // bf16 row into LDS for the MFMA transform (from f32 registers)
    union { unsigned short us[8]; uint4 u; } hb;
    hb.us[0] = f2bf(v0); hb.us[1] = f2bf(v1); hb.us[2] = f2bf(v2); hb.us[3] = f2bf(v3);
    hb.us[4] = f2bf(v4); hb.us[5] = f2bf(v5); hb.us[6] = f2bf(v6); hb.us[7] = f2bf(v7);
    *(uint4*)&Hs[n][sl * 8] = hb.u;
    if (sl == 0) Dv[n] = dv;
    __syncthreads();    // orders Ws + Hs + Dv stores before phase-2 reads

    // ---- phase 2: y = (H @ W) * dinv, 8 output tiles over 4 waves ----
    int wave = t >> 6, lane = t & 63;
    int rt   = wave & 1;               // row tile (16 rows)
    int ct0  = (wave >> 1) * 2;        // first of 2 col tiles
    f32x4 acc0 = (f32x4){0.f, 0.f, 0.f, 0.f}, acc1 = acc0;
    #pragma unroll
    for (int ks = 0; ks < 2; ++ks) {
        short8_t af = *(const short8_t*)&Hs[rt * 16 + (lane & 15)][ks * 32 + (lane >> 4) * 8];
        short8_t b0 = *(const short8_t*)&Ws[((ct0 * 2 + ks) * 64 + lane) * 8];
        short8_t b1 = *(const short8_t*)&Ws[(((ct0 + 1) * 2 + ks) * 64 + lane) * 8];
        acc0 = __builtin_amdgcn_mfma_f32_16x16x32_bf16(af, b0, acc0, 0, 0, 0);
        acc1 = __builtin_amdgcn_mfma_f32_16x16x32_bf16(af, b1, acc1, 0, 0, 0);
    }
    int cb = lane & 15, rq = lane >> 4;
    #pragma unroll
    for (int r = 0; r < 4; ++r) {
        int row = rt * 16 + rq * 4 + r;
        float dv2 = Dv[row];
        size_t go = (size_t)(blockIdx.x * 32 + row) * 64;
        yout[go + ct0 * 16 + cb]       = (_Float16)(acc0[r] * dv2);
        yout[go + (ct0 + 1) * 16 + cb] = (_Float16)(acc1[r] * dv2);
    }
}

__global__ __launch_bounds__(256, 6) void aggcv0_kernel(
    const uint4* y, const int* rp, const int* col, const float* dinv, const float* b,
    const unsigned short* Wp, _Float16* h, _Float16* yout) {
    aggcv_body<false, true>(y, rp, col, dinv, b, Wp, h, yout);   // z0 input: per-edge dinv
}
__global__ __launch_bounds__(256, 6) void aggcv1_kernel(
    const uint4* y, const int* rp, const int* col, const float* dinv, const float* b,
    const unsigned short* Wp, _Float16* h, _Float16* yout) {
    aggcv_body<true, false>(y, rp, col, dinv, b, Wp, h, yout);
}

// ---------------- CSR aggregation, final layer (bf16 out for ep) ------------
__global__ __launch_bounds__(256, 6) void agg2_kernel(
    const uint4* __restrict__ y4, const int* __restrict__ row_ptr, const int* __restrict__ col,
    const float* __restrict__ dinv, const float* __restrict__ bias,
    const _Float16* __restrict__ hprev, uint4* __restrict__ hb4)
{
    int v  = blockIdx.x * 32 + (threadIdx.x >> 3);
    int sl = threadIdx.x & 7;
    if (v >= N_NODES) return;

    float s[8];
    {
        uint4 a = y4[(size_t)v * 8 + sl];              // self loop
        float2 g;
        g = up16(a.x); s[0] = g.x; s[1] = g.y;  g = up16(a.y); s[2] = g.x; s[3] = g.y;
        g = up16(a.z); s[4] = g.x; s[5] = g.y;  g = up16(a.w); s[6] = g.x; s[7] = g.y;
    }
    auto accrow = [&](uint4 f) {
        float2 g;
        g = up16(f.x); s[0] += g.x; s[1] += g.y;  g = up16(f.y); s[2] += g.x; s[3] += g.y;
        g = up16(f.z); s[4] += g.x; s[5] += g.y;  g = up16(f.w); s[6] += g.x; s[7] += g.y;
    };

    int rs = row_ptr[v], re = row_ptr[v + 1];
    int i = rs;
    for (; i + 7 < re; i += 8) {
        int u0 = col[i],     u1 = col[i + 1], u2 = col[i + 2], u3 = col[i + 3];
        int u4 = col[i + 4], u5 = col[i + 5], u6 = col[i + 6], u7 = col[i + 7];
        uint4 f0 = y4[(size_t)u0 * 8 + sl];
        uint4 f1 = y4[(size_t)u1 * 8 + sl];
        uint4 f2 = y4[(size_t)u2 * 8 + sl];
        uint4 f3 = y4[(size_t)u3 * 8 + sl];
        uint4 f4 = y4[(size_t)u4 * 8 + sl];
        uint4 f5 = y4[(size_t)u5 * 8 + sl];
        uint4 f6 = y4[(size_t)u6 * 8 + sl];
        uint4 f7 = y4[(size_t)u7 * 8 + sl];
        accrow(f0); accrow(f1); accrow(f2); accrow(f3);
        accrow(f4); accrow(f5); accrow(f6); accrow(f7);
    }
    for (; i + 3 < re; i += 4) {
        int u0 = col[i], u1 = col[i + 1], u2 = col[i + 2], u3 = col[i + 3];
        uint4 f0 = y4[(size_t)u0 * 8 + sl];
        uint4 f1 = y4[(size_t)u1 * 8 + sl];
        uint4 f2 = y4[(size_t)u2 * 8 + sl];
        uint4 f3 = y4[(size_t)u3 * 8 + sl];
        accrow(f0); accrow(f1); accrow(f2); accrow(f3);
    }
    for (; i < re; ++i) accrow(y4[(size_t)col[i] * 8 + sl]);

    float dv = dinv[v];
    float4 ba = *(const float4*)&bias[sl * 8];
    float4 bb = *(const float4*)&bias[sl * 8 + 4];
    float v0 = fmaxf(dv * s[0] + ba.x, 0.f), v1 = fmaxf(dv * s[1] + ba.y, 0.f);
    float v2 = fmaxf(dv * s[2] + ba.z, 0.f), v3 = fmaxf(dv * s[3] + ba.w, 0.f);
    float v4 = fmaxf(dv * s[4] + bb.x, 0.f), v5 = fmaxf(dv * s[5] + bb.y, 0.f);
    float v6 = fmaxf(dv * s[6] + bb.z, 0.f), v7 = fmaxf(dv * s[7] + bb.w, 0.f);
    {
        uint4 hr = *(const uint4*)&hprev[(size_t)v * 64 + sl * 8];
        float2 g;
        g = up16(hr.x); v0 += g.x; v1 += g.y;  g = up16(hr.y); v2 += g.x; v3 += g.y;
        g = up16(hr.z); v4 += g.x; v5 += g.y;  g = up16(hr.w); v6 += g.x; v7 += g.y;
    }
    uint4 p;
    p.x = (unsigned)f2bf(v0) | ((unsigned)f2bf(v1) << 16);
    p.y = (unsigned)f2bf(v2) | ((unsigned)f2bf(v3) << 16);
    p.z = (unsigned)f2bf(v4) | ((unsigned)f2bf(v5) << 16);
    p.w = (unsigned)f2bf(v6) | ((unsigned)f2bf(v7) << 16);
    hb4[(size_t)v * 8 + sl] = p;
}

// ---------------- fused edge predictor ----------------
__global__ __launch_bounds__(256, 4) void mfma_ep12(
    const unsigned short* __restrict__ A, const int* __restrict__ gidx,
    const unsigned short* __restrict__ Wp1, const float* __restrict__ b1,
    const unsigned short* __restrict__ Wp2, const float* __restrict__ b2,
    const float* __restrict__ w3, const float* __restrict__ b3,
    float* __restrict__ out, int M)
{
    __shared__ __align__(16) unsigned short smem[12800];    // 25600 B
    unsigned short (*As)[72] = (unsigned short(*)[72])smem;
    unsigned short* Wls = smem + 4608;

    int t = threadIdx.x, wave = t >> 6, lane = t & 63;
    int m0 = blockIdx.x * 64;
    int cb = lane & 15, rq = lane >> 4;

    f32x4 acc[8];
    #pragma unroll
    for (int nt = 0; nt < 8; ++nt) acc[nt] = (f32x4){0.f, 0.f, 0.f, 0.f};

    for (int ch = 0; ch < 2; ++ch) {
        #pragma unroll
        for (int j = 0; j < 2; ++j) {
            int idx = t + j * 256;
            int row = idx >> 3, seg = idx & 7;
            int gr = m0 + row;
            uint4 v = make_uint4(0u, 0u, 0u, 0u);
            if (gr < M) {
                int node = (ch == 0) ? gidx[gr] : gidx[N_EL + gr];
                v = *(const uint4*)(A + (size_t)node * 64 + seg * 8);
            }
            *(uint4*)&As[row][seg * 8] = v;
        }
        #pragma unroll
        for (int j = 0; j < 4; ++j) {
            int idx = t + j * 256;
            ((uint4*)Wls)[idx] = ((const uint4*)(Wp1 + (size_t)ch * 8192))[idx];
        }
        __syncthreads();

        #pragma unroll
        for (int ks = 0; ks < 2; ++ks) {
            short8_t af = *(const short8_t*)&As[wave * 16 + cb][ks * 32 + rq * 8];
            #pragma unroll
            for (int nt = 0; nt < 8; ++nt) {
                short8_t bf = *(const short8_t*)&Wls[((nt * 2 + ks) * 64 + lane) * 8];
                acc[nt] = __builtin_amdgcn_mfma_f32_16x16x32_bf16(af, bf, acc[nt], 0, 0, 0);
            }
        }
        __syncthreads();
    }

    // ---- stage 2 prep: e1 -> LDS (bf16), W2 -> LDS ----
    unsigned short (*E1)[136] = (unsigned short(*)[136])smem;
    unsigned short* W2s = smem + 8704;
    #pragma unroll
    for (int nt = 0; nt < 8; ++nt) {
        int col = nt * 16 + cb;
        float bv = b1[col];
        #pragma unroll
        for (int r = 0; r < 4; ++r) {
            int row = wave * 16 + rq * 4 + r;
            E1[row][col] = f2bf(fmaxf(acc[nt][r] + bv, 0.f));
        }
    }
    ((uint4*)W2s)[t]       = ((const uint4*)Wp2)[t];
    ((uint4*)W2s)[t + 256] = ((const uint4*)Wp2)[t + 256];
    __syncthreads();

    // ---- stage 2 MFMA: NT16=4, NCH=2 over the 128-wide e1 ----
    f32x4 acc2[4];
    #pragma unroll
    for (int nt = 0; nt < 4; ++nt) acc2[nt] = (f32x4){0.f, 0.f, 0.f, 0.f};
    #pragma unroll
    for (int ch = 0; ch < 2; ++ch) {
        #pragma unroll
        for (int ks = 0; ks < 2; ++ks) {
            short8_t af = *(const short8_t*)&E1[wave * 16 + cb][ch * 64 + ks * 32 + rq * 8];
            #pragma unroll
            for (int nt = 0; nt < 4; ++nt) {
                short8_t bf = *(const short8_t*)&W2s[(((ch * 4 + nt) * 2 + ks) * 64 + lane) * 8];
                acc2[nt] = __builtin_amdgcn_mfma_f32_16x16x32_bf16(af, bf, acc2[nt], 0, 0, 0);
            }
        }
    }

    // ---- epilogue: relu + dot(w3) + sigmoid ----
    float s0 = 0.f, s1 = 0.f, s2 = 0.f, s3 = 0.f;
    #pragma unroll
    for (int nt = 0; nt < 4; ++nt) {
        int col = nt * 16 + cb;
        float bv = b2[col], wv = w3[col];
        s0 += fmaxf(acc2[nt][0] + bv, 0.f) * wv;
        s1 += fmaxf(acc2[nt][1] + bv, 0.f) * wv;
        s2 += fmaxf(acc2[nt][2] + bv, 0.f) * wv;
        s3 += fmaxf(acc2[nt][3] + bv, 0.f) * wv;
    }
    #pragma unroll
    for (int off = 1; off < 16; off <<= 1) {
        s0 += __shfl_xor(s0, off);
        s1 += __shfl_xor(s1, off);
        s2 += __shfl_xor(s2, off);
        s3 += __shfl_xor(s3, off);
    }
    if (cb == 0) {
        int gr = m0 + wave * 16 + rq * 4;
        if (gr + 3 < M) {
            float bb = b3[0];
            float4 o;
            o.x = 1.f / (1.f + expf(-(s0 + bb)));
            o.y = 1.f / (1.f + expf(-(s1 + bb)));
            o.z = 1.f / (1.f + expf(-(s2 + bb)));
            o.w = 1.f / (1.f + expf(-(s3 + bb)));
            *(float4*)&out[gr] = o;
        }
    }
}

extern "C" void kernel_launch(void* const* d_in, const int* in_sizes, int n_in,
                              void* d_out, int out_size, void* d_ws, size_t ws_size,
                              hipStream_t stream) {
    const float* x       = (const float*)d_in[0];
    const int*   ei      = (const int*)d_in[1];
    const int*   eli     = (const int*)d_in[2];
    const float* enc_w1  = (const float*)d_in[3];
    const float* enc_b1  = (const float*)d_in[4];
    const float* enc_w2  = (const float*)d_in[5];
    const float* enc_b2  = (const float*)d_in[6];
    const float* conv_w0 = (const float*)d_in[7];
    const float* conv_b0 = (const float*)d_in[8];
    const float* conv_w1 = (const float*)d_in[9];
    const float* conv_b1 = (const float*)d_in[10];
    const float* conv_w2 = (const float*)d_in[11];
    const float* conv_b2 = (const float*)d_in[12];
    const float* ep_w1   = (const float*)d_in[13];
    const float* ep_b1   = (const float*)d_in[14];
    const float* ep_w2   = (const float*)d_in[15];
    const float* ep_b2   = (const float*)d_in[16];
    const float* ep_w3   = (const float*)d_in[17];
    const float* ep_b3   = (const float*)d_in[18];
    float* out = (float*)d_out;

    // ---- workspace layout (float offsets) ----
    float* fws = (float*)d_ws;
    _Float16* yb         = (_Float16*)fws;                       // f16 [100k,64] = 3.2M f
    _Float16* h16        = (_Float16*)(fws + 3200000);           // f16 [100k,64] residual state
    unsigned short* h64b = (unsigned short*)(fws + 9600000);     // bf16/f16 [100k,64] = 3.2M f
    int*   col     = (int*)(fws + 12800000);                     // 1.6M i
    int*   row_ptr = col + 1600000;                              // 100001 (padded)
    float* dinvp   = (float*)(row_ptr + 100032);
    unsigned short* w2p = (unsigned short*)(dinvp + 100000);     // enc_w2: 32768 us
    unsigned short* w0p = w2p + 32768;                           // conv_w0: 8192 us
    unsigned short* w1p = w0p + 8192;                            // ep_w1: 16384 us
    unsigned short* wp2 = w1p + 16384;                           // ep_w2: 8192 us
    unsigned short* w1e = wp2 + 8192;                            // enc_w1: 8192 us
    unsigned short* wc1p = w1e + 8192;                           // conv_w1: 4096 us
    unsigned short* wc2p = wc1p + 4096;                          // conv_w2: 4096 us
    int*   btail   = (int*)(wc2p + 4096);                        // 196 i (+pad to 256)
    int*   bscr    = btail + 256;                                // 196*12288 = 2.41M i

    // y double-buffer: h64b region is free until agg2 writes the final hb.
    _Float16* yb2 = (_Float16*)h64b;

    const int GBE = N_EL / 64;             // 3125
    const int GBA = N_NODES / 32;          // 3125 (exact: 100000 = 3125*32)

    // ---- D1: all weight swizzles + btail zero ----
    prep0<<<321, 256, 0, stream>>>(enc_w2, conv_w0, ep_w1, ep_w2, enc_w1, conv_w1, conv_w2,
                                   w2p, w0p, w1p, wp2, w1e, wc1p, wc2p, btail);

    // ---- D2: mega = CSR partition (512 blocks) || encoder->z0 (1563 blocks) ----
    mega_fill_enc<<<PART_NB + ENC_NB, 256, 0, stream>>>(ei, btail, bscr,
        x, w1e, enc_b1, w2p, enc_b2, w0p, yb);

    // ---- D3: CSR finalize (row_ptr, col, dinv) ----
    fill_place<<<KBUCK, 512, 0, stream>>>(btail, bscr, row_ptr, dinvp, col);

    // ---- D4: layer 1: agg(dinv.*z0) -> h0 (f16) ; y1 = (h0@W1)*dinv fused ----
    aggcv0_kernel<<<GBA, 256, 0, stream>>>((const uint4*)yb, row_ptr, col, dinvp, conv_b0,
                                           wc1p, h16, yb2);
    // ---- D5: layer 2: agg(y1) -> h1 (residual, f16) ; y2 = (h1@W2)*dinv fused ----
    aggcv1_kernel<<<GBA, 256, 0, stream>>>((const uint4*)yb2, row_ptr, col, dinvp, conv_b1,
                                           wc2p, h16, yb);
    // ---- D6: layer 3: agg(y2) -> h2 (residual), bf16 out for ep ----
    agg2_kernel<<<GBA, 256, 0, stream>>>((const uint4*)yb, row_ptr, col, dinvp, conv_b2,
                                         h16, (uint4*)h64b);

    // ---- D7: edge predictor: ep1+ep2+ep3 fused, e1 lives in LDS ----
    mfma_ep12<<<GBE, 256, 0, stream>>>(h64b, eli, w1p, ep_b1, wp2, ep_b2, ep_w3, ep_b3, out, N_EL);
}